// Round 4
// baseline (197.240 us; speedup 1.0000x reference)
//
#include <hip/hip_runtime.h>
#include <cmath>

#define E_ 4
#define L_ 10
#define M_ 512
#define F_ 128
#define S_ 1000
#define HH 328   // float2 slots per env in hist (36 left pad + 251 + right pad)

typedef unsigned int u32;

__device__ __forceinline__ float fexp2(float a){
#if __has_builtin(__builtin_amdgcn_exp2f)
  return __builtin_amdgcn_exp2f(a);
#else
  return exp2f(a);
#endif
}

// monotone float <-> uint mapping for atomic min/max
__device__ __forceinline__ u32 fenc(float f){
  u32 u = __float_as_uint(f);
  return (u & 0x80000000u) ? ~u : (u | 0x80000000u);
}
__device__ __forceinline__ float fdec(u32 k){
  return __uint_as_float((k & 0x80000000u) ? (k ^ 0x80000000u) : ~k);
}

// ws float layout:
// [1]=min key(u32) [2]=max key(u32)      (memset: zeros, then 0xFF patch on [1])
// [8 .. 5128)      stdS[40][128]   (atomic f32 partial sums)
// [5128 .. 10248)  stdS2[40][128]
// [10248..10253)   CB: 0=leftS 1=stepFS 2=rstd 3=hscale 4=inv2step
// [10256..10512)   corr[256]  (offset^(x_c^2))
// [10512..10650)   K2 taps (69 float2)
// [10752..18432)   dpair[6][1280]
// [18944.. )       projT[E][L][F][M]  (unscaled, m contiguous)

// projU^T = matrix @ params (UNSCALED), + global min/max, + std partial sums
__global__ __launch_bounds__(256) void k_gemm(const float* __restrict__ mat,
                       const float* __restrict__ par,
                       float* __restrict__ projT, float* __restrict__ wsf){
  __shared__ float P[F_*F_];                 // 64KB params
  __shared__ float A[2176];                  // A[16][128] staging, then At[128][17]
  __shared__ float R[256];
  int b = blockIdx.x;       // 1280 = 40 * 32
  int el = b >> 5;          // 0..39
  int mt = (b & 31) * 16;   // row tile start
  int tid = threadIdx.x;
  for (int idx = tid; idx < F_*F_; idx += 256) P[idx] = par[idx];
  const float* abase = mat + ((size_t)el * M_ + mt) * F_;
  for (int idx = tid; idx < 2048; idx += 256) A[idx] = abase[idx];
  __syncthreads();
  int g = tid & 127, half = tid >> 7;
  float o[8];
  #pragma unroll
  for (int r=0;r<8;r++) o[r]=0.f;
  for (int k=0;k<F_;k+=4){
    float pk0 = P[(k+0)*F_+g];
    float pk1 = P[(k+1)*F_+g];
    float pk2 = P[(k+2)*F_+g];
    float pk3 = P[(k+3)*F_+g];
    #pragma unroll
    for (int r=0;r<8;r++){
      const float4 a = *(const float4*)&A[(half*8+r)*F_ + k];
      float t = o[r];
      t = fmaf(a.x, pk0, t);
      t = fmaf(a.y, pk1, t);
      t = fmaf(a.z, pk2, t);
      t = fmaf(a.w, pk3, t);
      o[r] = t;
    }
  }
  // std partials for this tile: per column g, sum/sumsq over the 16 rows
  float s = 0.f, s2 = 0.f;
  #pragma unroll
  for (int r=0;r<8;r++){
    float v = A[(half*8+r)*F_ + g];
    s += v; s2 += v*v;
  }
  R[tid] = s; __syncthreads();
  if (tid < 128) atomicAdd(&wsf[8 + el*F_ + tid], R[tid] + R[tid+128]);
  __syncthreads();
  R[tid] = s2; __syncthreads();
  if (tid < 128) atomicAdd(&wsf[5128 + el*F_ + tid], R[tid] + R[tid+128]);
  __syncthreads();
  // transpose tile through LDS: At[f][m16] with pad-17 stride (conflict-free writes)
  #pragma unroll
  for (int r=0;r<8;r++) A[g*17 + half*8 + r] = o[r];
  __syncthreads();
  // store 64B-aligned runs: 4 lanes cover one f-row's 16 floats
  #pragma unroll
  for (int rd=0; rd<2; rd++){
    int fr = rd*64 + (tid >> 2);
    int mi = (tid & 3) * 4;
    float4 v = make_float4(A[fr*17+mi], A[fr*17+mi+1], A[fr*17+mi+2], A[fr*17+mi+3]);
    *(float4*)(projT + ((size_t)el * F_ + fr) * M_ + mt + mi) = v;
  }
  // global min/max (unscaled; scaling by rstd>0 is monotone)
  float lmin = 3.4e38f, lmax = -3.4e38f;
  #pragma unroll
  for (int r=0;r<8;r++){
    lmin = fminf(lmin, o[r]);
    lmax = fmaxf(lmax, o[r]);
  }
  R[tid] = lmin; __syncthreads();
  for (int s1=128; s1>=1; s1>>=1){ if (tid<s1) R[tid]=fminf(R[tid],R[tid+s1]); __syncthreads(); }
  if (tid==0) atomicMin(((u32*)wsf)+1, fenc(R[0]));
  __syncthreads();
  R[tid] = lmax; __syncthreads();
  for (int s1=128; s1>=1; s1>>=1){ if (tid<s1) R[tid]=fmaxf(R[tid],R[tid+s1]); __syncthreads(); }
  if (tid==0) atomicMax(((u32*)wsf)+2, fenc(R[0]));
}

// single block: reduce stds -> rstd; scaled grid constants; conv-tap & corr tables
__global__ void k_red(float* __restrict__ wsf, float k2c, float divisor){
  __shared__ float rs[256];
  __shared__ float bc[2];
  int tid = threadIdx.x;
  float s = 0.f;
  for (int i = tid; i < 5120; i += 256){
    float a  = wsf[8 + i];
    float a2 = wsf[5128 + i];
    float mean = a * (1.0f/512.0f);
    float var  = a2 * (1.0f/512.0f) - mean*mean;
    s += sqrtf(fmaxf(var, 0.0f));
  }
  rs[tid] = s; __syncthreads();
  for (int g=128; g>=1; g>>=1){ if (tid<g) rs[tid]+=rs[tid+g]; __syncthreads(); }
  if (tid == 0){
    float rstd = 5120.0f / rs[0];
    u32* wsu = (u32*)wsf;
    float leftS  = fdec(wsu[1]) * rstd;
    float rightS = fdec(wsu[2]) * rstd;
    float stepFS = (rightS - leftS) * (1.0f/999.0f);
    wsf[10248+0] = leftS;
    wsf[10248+1] = stepFS;
    wsf[10248+2] = rstd;
    wsf[10248+3] = ((rightS - leftS) * (1.0f/1000.0f)) * 0.5f / divisor;
    wsf[10248+4] = 1.0f / (2.0f * stepFS);
    bc[0] = leftS; bc[1] = stepFS;
  }
  __syncthreads();
  float leftS = bc[0], stepFS = bc[1];
  float sh = 2.0f * stepFS;                 // hist bin width
  if (tid < 69){
    int u = tid - 34;
    float d0 = (float)(2*u)   * sh;         // tap for parity phi=0
    float d1 = (float)(2*u-1) * sh;         // tap for parity phi=1
    ((float2*)(wsf + 10512))[tid] = make_float2(fexp2(k2c*d0*d0), fexp2(k2c*d1*d1));
  }
  // corr[c] = offset^(x_c^2), x_c = leftS + (c-1)*4*stepFS
  float xc = fmaf((float)(tid - 1), 4.0f*stepFS, leftS);
  wsf[10256 + tid] = fexp2(k2c * xc * xc);
}

// KDE via histogram splat (quadratic, half-fine bins) + 69-tap float2 FIR to
// coarse nodes, then cubic interp to the 1000-pt fine grid + pairwise L1.
// Block = (l,f). wave = env; lane+64r = coarse node.
__global__ __launch_bounds__(256) void k_kde(const float* __restrict__ projT,
                      const int* __restrict__ dlen,
                      const float* __restrict__ wsf, float* __restrict__ dpair){
  __shared__ __align__(16) float sp[2048];    // p[4][512], then st[4][256] in [0..1024)
  __shared__ __align__(16) float2 hh[4*HH];   // parity-interleaved hist per env
  __shared__ float red[32];
  int b = blockIdx.x;          // 0..1279
  int l = b >> 7, f = b & 127;
  int tid = threadIdx.x, wave = tid >> 6, lane = tid & 63;
  const float* CB = wsf + 10248;
  float leftS = CB[0], stepFS = CB[1], rstd = CB[2], inv2 = CB[4];
  // stage p scaled by rstd (coalesced float4 from projT)
  for (int idx = tid; idx < 512; idx += 256){
    int e = idx >> 7, mq = idx & 127;
    float4 v = ((const float4*)(projT + (((size_t)e * L_ + l) * F_ + f) * M_))[mq];
    v.x *= rstd; v.y *= rstd; v.z *= rstd; v.w *= rstd;
    ((float4*)sp)[idx] = v;
  }
  // zero hist (4*HH float2 = 656 float4)
  for (int idx = tid; idx < 656; idx += 256)
    ((float4*)hh)[idx] = make_float4(0.f,0.f,0.f,0.f);
  __syncthreads();
  // quadratic (TSC) splat: 3 consecutive float slots per sample
  float* hf = (float*)hh;
  #pragma unroll
  for (int i = 0; i < 8; i++){
    int idx = tid + 256*i;
    int e = idx >> 9;
    float p = sp[idx];
    float pos = (p - leftS) * inv2;          // in hist-bin units, [0, 499.5]
    float n = floorf(pos + 0.5f);
    float d = pos - n;                       // [-0.5, 0.5]
    float wm = 0.5f*(0.5f-d)*(0.5f-d);
    float wp = 0.5f*(0.5f+d)*(0.5f+d);
    float w0 = 0.75f - d*d;
    int base = e*(2*HH) + (int)n + 71;       // float index of bin n-1
    atomicAdd(&hf[base  ], wm);
    atomicAdd(&hf[base+1], w0);
    atomicAdd(&hf[base+2], wp);
  }
  __syncthreads();
  // FIR conv at coarse nodes + fold padding correction; write st into sp[0..1024)
  const float2* K2 = (const float2*)(wsf + 10512);
  const float* corr = wsf + 10256;
  float lenE = (float)dlen[wave*L_ + l];
  float rlen = 1.0f / lenE;
  float padc = 512.0f - lenE;
  #pragma unroll
  for (int r = 0; r < 4; r++){
    int c = r*64 + lane;
    const float2* hb = hh + wave*HH + (c + 69);   // read hb[-uu], uu=0..68
    float acc = 0.f;
    for (int uu = 0; uu < 69; uu++){
      float2 hv = hb[-uu];
      float2 kv = K2[uu];
      acc = fmaf(hv.x, kv.x, acc);
      acc = fmaf(hv.y, kv.y, acc);
    }
    sp[wave*256 + c] = (acc - padc * corr[c]) * rlen;
  }
  __syncthreads();
  // fine grid: r_e(t) via 4-pt Lagrange cubic on st, then pairwise L1
  float ps[6] = {0,0,0,0,0,0};
  #pragma unroll
  for (int r=0;r<4;r++){
    int t = tid + 256*r;
    if (t < S_){
      int cc = t >> 2;
      float u = (float)(t & 3) * 0.25f;
      float um1 = u - 1.0f, um2 = u - 2.0f, up1 = u + 1.0f;
      float w0 = -u * um1 * um2 * (1.0f/6.0f);
      float w1 = up1 * um1 * um2 * 0.5f;
      float w2 = -u * up1 * um2 * 0.5f;
      float w3 = u * up1 * um1 * (1.0f/6.0f);
      float rr[4];
      #pragma unroll
      for (int e=0;e<4;e++){
        const float* st = &sp[e*256 + cc];
        rr[e] = w0*st[0] + w1*st[1] + w2*st[2] + w3*st[3];
      }
      ps[0] += fabsf(rr[0]-rr[1]);
      ps[1] += fabsf(rr[0]-rr[2]);
      ps[2] += fabsf(rr[0]-rr[3]);
      ps[3] += fabsf(rr[1]-rr[2]);
      ps[4] += fabsf(rr[1]-rr[3]);
      ps[5] += fabsf(rr[2]-rr[3]);
    }
  }
  #pragma unroll
  for (int pr=0; pr<6; pr++){
    float v = ps[pr];
    #pragma unroll
    for (int d=32; d>=1; d>>=1) v += __shfl_xor(v, d, 64);
    if (lane == 0) red[wave*8 + pr] = v;
  }
  __syncthreads();
  if (tid < 6)
    dpair[tid*1280 + b] = red[tid] + red[8+tid] + red[16+tid] + red[24+tid];
}

// merged finalize: scale, masked max over pairs, then max over L + mean over F
__global__ void k_fin(const float* __restrict__ dpair, const float* __restrict__ wsf,
                      const int* __restrict__ istrain, float* __restrict__ out){
  __shared__ float str[1280], ste[1280];
  __shared__ float s1[128], s2[128];
  int tid = threadIdx.x;   // 256 threads, 1 block
  float hscale = wsf[10248+3];
  bool t0 = istrain[0]!=0, t1 = istrain[1]!=0, t2 = istrain[2]!=0, t3 = istrain[3]!=0;
  bool trn[6] = { t0&&t1, t0&&t2, t0&&t3, t1&&t2, t1&&t3, t2&&t3 };
  for (int idx = tid; idx < 1280; idx += 256){
    float tmax = -INFINITY, trmax = -INFINITY;
    #pragma unroll
    for (int pr=0;pr<6;pr++){
      float h = dpair[pr*1280 + idx] * hscale;
      tmax = fmaxf(tmax, h);
      if (trn[pr]) trmax = fmaxf(trmax, h);
    }
    out[idx]        = trmax;   // train_results
    out[1280 + idx] = tmax;    // test_results
    str[idx] = trmax; ste[idx] = tmax;
  }
  __syncthreads();
  if (tid < 128){
    float m1 = -INFINITY, m2 = -INFINITY;
    for (int l=0;l<L_;l++){
      m1 = fmaxf(m1, str[l*F_ + tid]);
      m2 = fmaxf(m2, ste[l*F_ + tid]);
    }
    s1[tid] = m1; s2[tid] = m2;
  }
  __syncthreads();
  for (int g=64; g>=1; g>>=1){
    if (tid < g){ s1[tid] += s1[tid+g]; s2[tid] += s2[tid+g]; }
    __syncthreads();
  }
  if (tid == 0){
    out[2560] = s1[0] * (1.0f/128.0f);
    out[2561] = s2[0] * (1.0f/128.0f);
  }
}

extern "C" void kernel_launch(void* const* d_in, const int* in_sizes, int n_in,
                              void* d_out, int out_size, void* d_ws, size_t ws_size,
                              hipStream_t stream){
  const float* mat = (const float*)d_in[0];
  const float* par = (const float*)d_in[1];
  const int*  dlen = (const int*)d_in[2];
  const int*  istr = (const int*)d_in[3];
  float* out   = (float*)d_out;
  float* wsf   = (float*)d_ws;
  float* dpair = wsf + 10752;
  float* projT = wsf + 18944;

  // host-computable constants (bw's data-dependent factor is identically 1)
  double bw_d   = 1.06 * pow(512.0, -0.2);
  float  bw     = (float)bw_d;
  float  offset = expf(-0.5f / (bw*bw));
  float  k2c    = (float)(log((double)offset) * 1.4426950408889634);  // log2(offset)
  float  divisor = sqrtf(6.283185307179586f) * bw;

  // init: zero keys + std partials, then set min-key to 0xFFFFFFFF
  hipMemsetAsync(wsf, 0, 10248 * sizeof(float), stream);
  hipMemsetAsync((char*)wsf + 4, 0xFF, 4, stream);

  k_gemm <<<1280, 256, 0, stream>>>(mat, par, projT, wsf);
  k_red  <<<1,    256, 0, stream>>>(wsf, k2c, divisor);
  k_kde  <<<1280, 256, 0, stream>>>(projT, dlen, wsf, dpair);
  k_fin  <<<1,    256, 0, stream>>>(dpair, wsf, istr, out);
}

// Round 5
// 184.192 us; speedup vs baseline: 1.0708x; 1.0708x over previous
//
#include <hip/hip_runtime.h>
#include <cmath>

#define E_ 4
#define L_ 10
#define M_ 512
#define F_ 128
#define S_ 1000
#define HH 328   // float2 slots per env in hist (36 left pad + 251 + right pad)

typedef unsigned int u32;
typedef _Float16 f16;
typedef __attribute__((ext_vector_type(8))) _Float16 v8h;
typedef __attribute__((ext_vector_type(4))) float v4f;

__device__ __forceinline__ float fexp2(float a){
#if __has_builtin(__builtin_amdgcn_exp2f)
  return __builtin_amdgcn_exp2f(a);
#else
  return exp2f(a);
#endif
}

// monotone float <-> uint mapping for atomic min/max
__device__ __forceinline__ u32 fenc(float f){
  u32 u = __float_as_uint(f);
  return (u & 0x80000000u) ? ~u : (u | 0x80000000u);
}
__device__ __forceinline__ float fdec(u32 k){
  return __uint_as_float((k & 0x80000000u) ? (k ^ 0x80000000u) : ~k);
}

// ws float layout:
// [1]=min key(u32) [2]=max key(u32)      (memset: zeros, then 0xFF patch on [1])
// [8 .. 5128)      stdS[40][128]   (atomic f32 partial sums)
// [5128 .. 10248)  stdS2[40][128]
// [10248..10253)   CB: 0=leftS 1=stepFS 2=rstd 3=hscale 4=inv2step
// [10256..10512)   corr[256]  (offset^(x_c^2))
// [10512..10650)   K2 taps (69 float2)
// [10752..18432)   dpair[6][1280]
// [18432..26624)   parT f16[128][128]  (params transposed, g-major)
// [26624.. )       projT[E][L][F][M]   (unscaled, m contiguous)

// blocks 0..159: std partial sums over mat; blocks 160..191: par -> parT f16
__global__ void k_std(const float* __restrict__ mat, const float* __restrict__ par,
                      float* __restrict__ wsf){
  if (blockIdx.x >= 160){
    int base = (blockIdx.x - 160) * 512;
    f16* parT = (f16*)(wsf + 18432);
    for (int i = threadIdx.x; i < 512; i += 256){
      int idx = base + i;                       // idx = g*128 + f
      parT[idx] = (f16)par[(idx & 127) * 128 + (idx >> 7)];
    }
    return;
  }
  __shared__ float S1[256], S2[256];
  int el = blockIdx.x >> 2, q = blockIdx.x & 3;
  int tid = threadIdx.x, f = tid & 127, part = tid >> 7;
  const float* base = mat + ((size_t)el * M_ + q*128 + part*64) * F_;
  float s = 0.f, s2 = 0.f;
  for (int i = 0; i < 64; i++){
    float v = base[i*F_ + f];
    s += v; s2 += v*v;
  }
  S1[tid] = s; S2[tid] = s2;
  __syncthreads();
  if (tid < 128){
    atomicAdd(&wsf[8    + el*F_ + tid], S1[tid] + S1[tid+128]);
    atomicAdd(&wsf[5128 + el*F_ + tid], S2[tid] + S2[tid+128]);
  }
}

// MFMA f16 GEMM: projT[el][g][m] = sum_f mat[el][m][f]*par[f][g], + global min/max.
// Block = 16 rows x 128 cols; wave w covers cols 32w..32w+32 (2 mfma per k-chunk).
__global__ __launch_bounds__(256) void k_gemm(const float* __restrict__ mat,
                       const f16* __restrict__ parT,
                       float* __restrict__ projT, float* __restrict__ wsf){
  __shared__ __align__(16) f16 PT[128*136];   // 34.0KB [n][k], row stride 136
  __shared__ __align__(16) f16 AT[16*136];    // 4.25KB [m][k], row stride 136
  __shared__ float CT[128*17];                // 8.5KB  [n][m], row stride 17
  __shared__ float RMM[16];
  int b = blockIdx.x;        // 1280 = 40 * 32
  int el = b >> 5, mt = (b & 31) * 16;
  int tid = threadIdx.x, lane = tid & 63, wave = tid >> 6;
  // stage PT (f16, already transposed): 2048 x 16B
  for (int i = tid; i < 2048; i += 256){
    int n = i >> 4, kq = i & 15;
    *(float4*)&PT[n*136 + kq*8] = ((const float4*)parT)[i];
  }
  // stage A tile f32 -> f16
  const float* ab = mat + ((size_t)el * M_ + mt) * F_;
  for (int i = tid; i < 2048; i += 256)
    AT[(i >> 7)*136 + (i & 127)] = (f16)ab[i];
  __syncthreads();
  int q = lane >> 4, m16 = lane & 15;   // A-frag: m=lane&15; B-frag: n=lane&15
  v4f acc0 = {0.f,0.f,0.f,0.f}, acc1 = {0.f,0.f,0.f,0.f};
  #pragma unroll
  for (int c = 0; c < 4; c++){
    v8h af = *(const v8h*)&AT[m16*136 + c*32 + q*8];
    v8h b0 = *(const v8h*)&PT[(wave*32 +      m16)*136 + c*32 + q*8];
    v8h b1 = *(const v8h*)&PT[(wave*32 + 16 + m16)*136 + c*32 + q*8];
    acc0 = __builtin_amdgcn_mfma_f32_16x16x32_f16(af, b0, acc0, 0, 0, 0);
    acc1 = __builtin_amdgcn_mfma_f32_16x16x32_f16(af, b1, acc1, 0, 0, 0);
  }
  // C/D layout: col(n)=lane&15, row(m)=q*4+reg  -> CT[n][m]
  #pragma unroll
  for (int r = 0; r < 4; r++){
    CT[(wave*32 +      m16)*17 + q*4 + r] = acc0[r];
    CT[(wave*32 + 16 + m16)*17 + q*4 + r] = acc1[r];
  }
  // wave min/max of its 8 outputs
  float lmin =  3.4e38f, lmax = -3.4e38f;
  #pragma unroll
  for (int r = 0; r < 4; r++){
    lmin = fminf(lmin, fminf(acc0[r], acc1[r]));
    lmax = fmaxf(lmax, fmaxf(acc0[r], acc1[r]));
  }
  #pragma unroll
  for (int d = 32; d >= 1; d >>= 1){
    lmin = fminf(lmin, __shfl_xor(lmin, d, 64));
    lmax = fmaxf(lmax, __shfl_xor(lmax, d, 64));
  }
  if (lane == 0){ RMM[wave] = lmin; RMM[8+wave] = lmax; }
  __syncthreads();
  // coalesced store: 4 lanes cover one f-row's 16 floats
  #pragma unroll
  for (int rd = 0; rd < 2; rd++){
    int fr = rd*64 + (tid >> 2);
    int mi = (tid & 3) * 4;
    float4 v = make_float4(CT[fr*17+mi], CT[fr*17+mi+1], CT[fr*17+mi+2], CT[fr*17+mi+3]);
    *(float4*)(projT + ((size_t)el * F_ + fr) * M_ + mt + mi) = v;
  }
  if (tid == 0){
    float mn = fminf(fminf(RMM[0], RMM[1]), fminf(RMM[2], RMM[3]));
    float mx = fmaxf(fmaxf(RMM[8], RMM[9]), fmaxf(RMM[10], RMM[11]));
    atomicMin(((u32*)wsf)+1, fenc(mn));
    atomicMax(((u32*)wsf)+2, fenc(mx));
  }
}

// single block: reduce stds -> rstd; scaled grid constants; conv-tap & corr tables
__global__ void k_red(float* __restrict__ wsf, float k2c, float divisor){
  __shared__ float rs[256];
  __shared__ float bc[2];
  int tid = threadIdx.x;
  float s = 0.f;
  for (int i = tid; i < 5120; i += 256){
    float a  = wsf[8 + i];
    float a2 = wsf[5128 + i];
    float mean = a * (1.0f/512.0f);
    float var  = a2 * (1.0f/512.0f) - mean*mean;
    s += sqrtf(fmaxf(var, 0.0f));
  }
  rs[tid] = s; __syncthreads();
  for (int g=128; g>=1; g>>=1){ if (tid<g) rs[tid]+=rs[tid+g]; __syncthreads(); }
  if (tid == 0){
    float rstd = 5120.0f / rs[0];
    u32* wsu = (u32*)wsf;
    float leftS  = fdec(wsu[1]) * rstd;
    float rightS = fdec(wsu[2]) * rstd;
    float stepFS = (rightS - leftS) * (1.0f/999.0f);
    wsf[10248+0] = leftS;
    wsf[10248+1] = stepFS;
    wsf[10248+2] = rstd;
    wsf[10248+3] = ((rightS - leftS) * (1.0f/1000.0f)) * 0.5f / divisor;
    wsf[10248+4] = 1.0f / (2.0f * stepFS);
    bc[0] = leftS; bc[1] = stepFS;
  }
  __syncthreads();
  float leftS = bc[0], stepFS = bc[1];
  float sh = 2.0f * stepFS;                 // hist bin width
  if (tid < 69){
    int u = tid - 34;
    float d0 = (float)(2*u)   * sh;         // tap for parity phi=0
    float d1 = (float)(2*u-1) * sh;         // tap for parity phi=1
    ((float2*)(wsf + 10512))[tid] = make_float2(fexp2(k2c*d0*d0), fexp2(k2c*d1*d1));
  }
  // corr[c] = offset^(x_c^2), x_c = leftS + (c-1)*4*stepFS
  float xc = fmaf((float)(tid - 1), 4.0f*stepFS, leftS);
  wsf[10256 + tid] = fexp2(k2c * xc * xc);
}

// KDE via per-wave histogram splat (wave = env) + LDS-tap FIR to coarse nodes,
// then cubic interp to the 1000-pt fine grid + pairwise L1. Block = (l,f).
__global__ __launch_bounds__(256) void k_kde(const float* __restrict__ projT,
                      const int* __restrict__ dlen,
                      const float* __restrict__ wsf, float* __restrict__ dpair){
  __shared__ __align__(16) float sp[2048];    // p[4][512], then st[4][256] in [0..1024)
  __shared__ __align__(16) float2 hh[4*HH];   // parity-interleaved hist per env
  __shared__ __align__(8) float sK[140];      // conv taps (138 floats)
  __shared__ float sCorr[256];
  __shared__ float red[32];
  int b = blockIdx.x;          // 0..1279
  int l = b >> 7, f = b & 127;
  int tid = threadIdx.x, wave = tid >> 6, lane = tid & 63;
  const float* CB = wsf + 10248;
  float leftS = CB[0], stepFS = CB[1], rstd = CB[2], inv2 = CB[4];
  // stage p scaled by rstd (coalesced float4 from projT)
  for (int idx = tid; idx < 512; idx += 256){
    int e = idx >> 7, mq = idx & 127;
    float4 v = ((const float4*)(projT + (((size_t)e * L_ + l) * F_ + f) * M_))[mq];
    v.x *= rstd; v.y *= rstd; v.z *= rstd; v.w *= rstd;
    ((float4*)sp)[idx] = v;
  }
  if (tid < 138) sK[tid] = wsf[10512 + tid];
  sCorr[tid] = wsf[10256 + tid];
  // zero hist (4*HH float2 = 656 float4)
  for (int idx = tid; idx < 656; idx += 256)
    ((float4*)hh)[idx] = make_float4(0.f,0.f,0.f,0.f);
  __syncthreads();
  // quadratic (TSC) splat; wave w owns env w's histogram (private region)
  {
    float* hf = (float*)(hh + wave*HH);
    const float* spw = sp + wave*512;
    #pragma unroll
    for (int i = 0; i < 8; i++){
      float p = spw[lane + 64*i];
      float pos = (p - leftS) * inv2;          // hist-bin units
      float n = floorf(pos + 0.5f);
      float d = pos - n;                       // [-0.5, 0.5]
      float wm = 0.5f*(0.5f-d)*(0.5f-d);
      float wp = 0.5f*(0.5f+d)*(0.5f+d);
      float w0 = 0.75f - d*d;
      int base = (int)n + 71;                  // float index of bin n-1
      atomicAdd(&hf[base  ], wm);
      atomicAdd(&hf[base+1], w0);
      atomicAdd(&hf[base+2], wp);
    }
  }
  __syncthreads();
  // FIR conv at coarse nodes, taps from LDS, 4 independent accumulators
  float lenE = (float)dlen[wave*L_ + l];
  float rlen = 1.0f / lenE;
  float padc = 512.0f - lenE;
  {
    const float* hb = (const float*)(hh + wave*HH);
    float a0=0.f, a1=0.f, a2=0.f, a3=0.f;
    #pragma unroll 3
    for (int uu = 0; uu < 69; uu++){
      float2 kv = *(const float2*)&sK[2*uu];
      int off = 2*(69 - uu) + 2*lane;          // float index, node c = lane (r=0)
      float2 h0 = *(const float2*)&hb[off];
      float2 h1 = *(const float2*)&hb[off + 128];
      float2 h2 = *(const float2*)&hb[off + 256];
      float2 h3 = *(const float2*)&hb[off + 384];
      a0 = fmaf(h0.x, kv.x, fmaf(h0.y, kv.y, a0));
      a1 = fmaf(h1.x, kv.x, fmaf(h1.y, kv.y, a1));
      a2 = fmaf(h2.x, kv.x, fmaf(h2.y, kv.y, a2));
      a3 = fmaf(h3.x, kv.x, fmaf(h3.y, kv.y, a3));
    }
    __syncthreads();   // waves done reading sp (splat); st overwrites sp[0..1024)
    sp[wave*256 + lane      ] = (a0 - padc * sCorr[lane      ]) * rlen;
    sp[wave*256 + lane +  64] = (a1 - padc * sCorr[lane +  64]) * rlen;
    sp[wave*256 + lane + 128] = (a2 - padc * sCorr[lane + 128]) * rlen;
    sp[wave*256 + lane + 192] = (a3 - padc * sCorr[lane + 192]) * rlen;
  }
  __syncthreads();
  // fine grid: r_e(t) via 4-pt Lagrange cubic on st, then pairwise L1
  float ps[6] = {0,0,0,0,0,0};
  #pragma unroll
  for (int r=0;r<4;r++){
    int t = tid + 256*r;
    if (t < S_){
      int cc = t >> 2;
      float u = (float)(t & 3) * 0.25f;
      float um1 = u - 1.0f, um2 = u - 2.0f, up1 = u + 1.0f;
      float w0 = -u * um1 * um2 * (1.0f/6.0f);
      float w1 = up1 * um1 * um2 * 0.5f;
      float w2 = -u * up1 * um2 * 0.5f;
      float w3 = u * up1 * um1 * (1.0f/6.0f);
      float rr[4];
      #pragma unroll
      for (int e=0;e<4;e++){
        const float* st = &sp[e*256 + cc];
        rr[e] = w0*st[0] + w1*st[1] + w2*st[2] + w3*st[3];
      }
      ps[0] += fabsf(rr[0]-rr[1]);
      ps[1] += fabsf(rr[0]-rr[2]);
      ps[2] += fabsf(rr[0]-rr[3]);
      ps[3] += fabsf(rr[1]-rr[2]);
      ps[4] += fabsf(rr[1]-rr[3]);
      ps[5] += fabsf(rr[2]-rr[3]);
    }
  }
  #pragma unroll
  for (int pr=0; pr<6; pr++){
    float v = ps[pr];
    #pragma unroll
    for (int d=32; d>=1; d>>=1) v += __shfl_xor(v, d, 64);
    if (lane == 0) red[wave*8 + pr] = v;
  }
  __syncthreads();
  if (tid < 6)
    dpair[tid*1280 + b] = red[tid] + red[8+tid] + red[16+tid] + red[24+tid];
}

// merged finalize: scale, masked max over pairs, then max over L + mean over F
__global__ void k_fin(const float* __restrict__ dpair, const float* __restrict__ wsf,
                      const int* __restrict__ istrain, float* __restrict__ out){
  __shared__ float str[1280], ste[1280];
  __shared__ float s1[128], s2[128];
  int tid = threadIdx.x;   // 256 threads, 1 block
  float hscale = wsf[10248+3];
  bool t0 = istrain[0]!=0, t1 = istrain[1]!=0, t2 = istrain[2]!=0, t3 = istrain[3]!=0;
  bool trn[6] = { t0&&t1, t0&&t2, t0&&t3, t1&&t2, t1&&t3, t2&&t3 };
  for (int idx = tid; idx < 1280; idx += 256){
    float tmax = -INFINITY, trmax = -INFINITY;
    #pragma unroll
    for (int pr=0;pr<6;pr++){
      float h = dpair[pr*1280 + idx] * hscale;
      tmax = fmaxf(tmax, h);
      if (trn[pr]) trmax = fmaxf(trmax, h);
    }
    out[idx]        = trmax;   // train_results
    out[1280 + idx] = tmax;    // test_results
    str[idx] = trmax; ste[idx] = tmax;
  }
  __syncthreads();
  if (tid < 128){
    float m1 = -INFINITY, m2 = -INFINITY;
    for (int l=0;l<L_;l++){
      m1 = fmaxf(m1, str[l*F_ + tid]);
      m2 = fmaxf(m2, ste[l*F_ + tid]);
    }
    s1[tid] = m1; s2[tid] = m2;
  }
  __syncthreads();
  for (int g=64; g>=1; g>>=1){
    if (tid < g){ s1[tid] += s1[tid+g]; s2[tid] += s2[tid+g]; }
    __syncthreads();
  }
  if (tid == 0){
    out[2560] = s1[0] * (1.0f/128.0f);
    out[2561] = s2[0] * (1.0f/128.0f);
  }
}

extern "C" void kernel_launch(void* const* d_in, const int* in_sizes, int n_in,
                              void* d_out, int out_size, void* d_ws, size_t ws_size,
                              hipStream_t stream){
  const float* mat = (const float*)d_in[0];
  const float* par = (const float*)d_in[1];
  const int*  dlen = (const int*)d_in[2];
  const int*  istr = (const int*)d_in[3];
  float* out   = (float*)d_out;
  float* wsf   = (float*)d_ws;
  float* dpair = wsf + 10752;
  const f16* parT = (const f16*)(wsf + 18432);
  float* projT = wsf + 26624;

  // host-computable constants (bw's data-dependent factor is identically 1)
  double bw_d   = 1.06 * pow(512.0, -0.2);
  float  bw     = (float)bw_d;
  float  offset = expf(-0.5f / (bw*bw));
  float  k2c    = (float)(log((double)offset) * 1.4426950408889634);  // log2(offset)
  float  divisor = sqrtf(6.283185307179586f) * bw;

  // init: zero keys + std partials, then set min-key to 0xFFFFFFFF
  hipMemsetAsync(wsf, 0, 10248 * sizeof(float), stream);
  hipMemsetAsync((char*)wsf + 4, 0xFF, 4, stream);

  k_std  <<<192,  256, 0, stream>>>(mat, par, wsf);
  k_gemm <<<1280, 256, 0, stream>>>(mat, parT, projT, wsf);
  k_red  <<<1,    256, 0, stream>>>(wsf, k2c, divisor);
  k_kde  <<<1280, 256, 0, stream>>>(projT, dlen, wsf, dpair);
  k_fin  <<<1,    256, 0, stream>>>(dpair, wsf, istr, out);
}

// Round 6
// 182.333 us; speedup vs baseline: 1.0818x; 1.0102x over previous
//
#include <hip/hip_runtime.h>
#include <cmath>

#define E_ 4
#define L_ 10
#define M_ 512
#define F_ 128
#define S_ 1000

typedef unsigned int u32;
typedef _Float16 f16;
typedef __attribute__((ext_vector_type(8))) _Float16 v8h;
typedef __attribute__((ext_vector_type(4))) float v4f;

__device__ __forceinline__ float fexp2(float a){
#if __has_builtin(__builtin_amdgcn_exp2f)
  return __builtin_amdgcn_exp2f(a);
#else
  return exp2f(a);
#endif
}

__device__ __forceinline__ u32 fenc(float f){
  u32 u = __float_as_uint(f);
  return (u & 0x80000000u) ? ~u : (u | 0x80000000u);
}
__device__ __forceinline__ float fdec(u32 k){
  return __uint_as_float((k & 0x80000000u) ? (k ^ 0x80000000u) : ~k);
}

// ws float layout (total 280576 < 288768 proven available):
// [1]=min key [2]=max key          (init by k_std block 0)
// [8..13)    CB: 0=leftS 1=stepFS 2=rstd 3=hscale 4=inv2step
// [48..304)  corr[256]
// [304..448) K2 taps (72 float2, last 3 zero)
// [448..5568)   S1 partials [40][128]   (non-atomic, unique slot per block)
// [5568..10688) S2 partials [40][128]
// [10752..18432) dpair[6][1280]
// [18432..280576) projT[E][L][F][M] (unscaled, m contiguous)

// 40 blocks x 512 thr: per-(e,l) std partial sums (no atomics); block 0 inits keys
__global__ void k_std(const float* __restrict__ mat, float* __restrict__ wsf){
  __shared__ float S1[512], S2[512];
  int b = blockIdx.x, tid = threadIdx.x;
  if (b == 0 && tid == 0){
    ((u32*)wsf)[1] = 0xFFFFFFFFu;
    ((u32*)wsf)[2] = 0u;
  }
  int f = tid & 127, part = tid >> 7;
  const float* base = mat + ((size_t)b * M_ + part*128) * F_;
  float s = 0.f, s2 = 0.f;
  for (int i = 0; i < 128; i++){
    float v = base[i*F_ + f];
    s += v; s2 += v*v;
  }
  S1[tid] = s; S2[tid] = s2;
  __syncthreads();
  if (tid < 128){
    wsf[448  + b*128 + tid] = S1[tid] + S1[tid+128] + S1[tid+256] + S1[tid+384];
    wsf[5568 + b*128 + tid] = S2[tid] + S2[tid+128] + S2[tid+256] + S2[tid+384];
  }
}

// MFMA f16 GEMM, no LDS staging: A/B frags loaded straight from global with
// inline f32->f16 cvt; C stored from registers (row=q*4+r is m-contiguous).
__global__ __launch_bounds__(256) void k_gemm(const float* __restrict__ mat,
                       const float* __restrict__ par,
                       float* __restrict__ projT, float* __restrict__ wsf){
  __shared__ float RMM[16];
  int b = blockIdx.x;        // 1280 = 40 * 32
  int el = b >> 5, mt = (b & 31) * 16;
  int tid = threadIdx.x, lane = tid & 63, wave = tid >> 6;
  int q = (lane >> 4) & 3, m16 = lane & 15;
  const float* arow = mat + ((size_t)el * M_ + mt + m16) * F_;
  v4f acc0 = {0.f,0.f,0.f,0.f}, acc1 = {0.f,0.f,0.f,0.f};
  #pragma unroll
  for (int c = 0; c < 4; c++){
    float4 a0 = *(const float4*)&arow[c*32 + q*8];
    float4 a1 = *(const float4*)&arow[c*32 + q*8 + 4];
    v8h af, b0, b1;
    af[0]=(f16)a0.x; af[1]=(f16)a0.y; af[2]=(f16)a0.z; af[3]=(f16)a0.w;
    af[4]=(f16)a1.x; af[5]=(f16)a1.y; af[6]=(f16)a1.z; af[7]=(f16)a1.w;
    const float* pb = par + (c*32 + q*8)*F_ + wave*32 + m16;
    #pragma unroll
    for (int j = 0; j < 8; j++){
      b0[j] = (f16)pb[j*F_];
      b1[j] = (f16)pb[j*F_ + 16];
    }
    acc0 = __builtin_amdgcn_mfma_f32_16x16x32_f16(af, b0, acc0, 0, 0, 0);
    acc1 = __builtin_amdgcn_mfma_f32_16x16x32_f16(af, b1, acc1, 0, 0, 0);
  }
  // direct stores: C/D row=q*4+r (m), col=m16 (n) -> projT[el][n][m]
  *(float4*)(projT + ((size_t)el*F_ + wave*32      + m16)*M_ + mt + q*4)
      = make_float4(acc0[0], acc0[1], acc0[2], acc0[3]);
  *(float4*)(projT + ((size_t)el*F_ + wave*32 + 16 + m16)*M_ + mt + q*4)
      = make_float4(acc1[0], acc1[1], acc1[2], acc1[3]);
  // min/max: wave shfl-reduce -> LDS -> 2 atomics per block
  float lmin =  3.4e38f, lmax = -3.4e38f;
  #pragma unroll
  for (int r = 0; r < 4; r++){
    lmin = fminf(lmin, fminf(acc0[r], acc1[r]));
    lmax = fmaxf(lmax, fmaxf(acc0[r], acc1[r]));
  }
  #pragma unroll
  for (int d = 32; d >= 1; d >>= 1){
    lmin = fminf(lmin, __shfl_xor(lmin, d, 64));
    lmax = fmaxf(lmax, __shfl_xor(lmax, d, 64));
  }
  if (lane == 0){ RMM[wave] = lmin; RMM[8+wave] = lmax; }
  __syncthreads();
  if (tid == 0){
    float mn = fminf(fminf(RMM[0], RMM[1]), fminf(RMM[2], RMM[3]));
    float mx = fmaxf(fmaxf(RMM[8], RMM[9]), fmaxf(RMM[10], RMM[11]));
    atomicMin(((u32*)wsf)+1, fenc(mn));
    atomicMax(((u32*)wsf)+2, fenc(mx));
  }
}

// single block: reduce stds -> rstd; grid constants; conv-tap & corr tables
__global__ void k_red(float* __restrict__ wsf, float k2c, float divisor){
  __shared__ float rs[256];
  __shared__ float bc[2];
  int tid = threadIdx.x;
  float s = 0.f;
  for (int i = tid; i < 5120; i += 256){
    float a  = wsf[448  + i];
    float a2 = wsf[5568 + i];
    float mean = a * (1.0f/512.0f);
    float var  = a2 * (1.0f/512.0f) - mean*mean;
    s += sqrtf(fmaxf(var, 0.0f));
  }
  rs[tid] = s; __syncthreads();
  for (int g=128; g>=1; g>>=1){ if (tid<g) rs[tid]+=rs[tid+g]; __syncthreads(); }
  if (tid == 0){
    float rstd = 5120.0f / rs[0];
    u32* wsu = (u32*)wsf;
    float leftS  = fdec(wsu[1]) * rstd;
    float rightS = fdec(wsu[2]) * rstd;
    float stepFS = (rightS - leftS) * (1.0f/999.0f);
    wsf[8+0] = leftS;
    wsf[8+1] = stepFS;
    wsf[8+2] = rstd;
    wsf[8+3] = ((rightS - leftS) * (1.0f/1000.0f)) * 0.5f / divisor;
    wsf[8+4] = 1.0f / (2.0f * stepFS);
    bc[0] = leftS; bc[1] = stepFS;
  }
  __syncthreads();
  float leftS = bc[0], stepFS = bc[1];
  float sh = 2.0f * stepFS;                 // hist bin width
  if (tid < 72){
    int u = tid - 34;
    float d0 = (float)(2*u)   * sh;
    float d1 = (float)(2*u-1) * sh;
    float2 t = (tid < 69) ? make_float2(fexp2(k2c*d0*d0), fexp2(k2c*d1*d1))
                          : make_float2(0.f, 0.f);
    ((float2*)(wsf + 304))[tid] = t;
  }
  float xc = fmaf((float)(tid - 1), 4.0f*stepFS, leftS);
  wsf[48 + tid] = fexp2(k2c * xc * xc);
}

// KDE: per-wave hist splat (wave=env) + 72-tap unrolled FIR + cubic interp + L1.
// Single hand-placed smem block: p/st [0..2048) | hist [2048..4672) |
// taps [4672..4816) | corr [4816..5072) | red [5072..5104)
__global__ __launch_bounds__(256) void k_kde(const float* __restrict__ projT,
                      const int* __restrict__ dlen,
                      const float* __restrict__ wsf, float* __restrict__ dpair){
  __shared__ __align__(16) float smem[5104];
  int b = blockIdx.x;          // 0..1279
  int l = b >> 7, f = b & 127;
  int tid = threadIdx.x, wave = tid >> 6, lane = tid & 63;
  const float* CB = wsf + 8;
  float leftS = CB[0], rstd = CB[2], inv2 = CB[4];
  // stage p scaled by rstd (coalesced float4)
  for (int idx = tid; idx < 512; idx += 256){
    int e = idx >> 7, mq = idx & 127;
    float4 v = ((const float4*)(projT + (((size_t)e * L_ + l) * F_ + f) * M_))[mq];
    v.x *= rstd; v.y *= rstd; v.z *= rstd; v.w *= rstd;
    ((float4*)smem)[idx] = v;
  }
  if (tid < 144) smem[4672 + tid] = wsf[304 + tid];
  smem[4816 + tid] = wsf[48 + tid];
  for (int idx = tid; idx < 656; idx += 256)
    ((float4*)(smem + 2048))[idx] = make_float4(0.f,0.f,0.f,0.f);
  __syncthreads();
  // quadratic (TSC) splat; wave w owns env w's histogram; preload 8 samples
  {
    float* hf = smem + 2048 + wave*656;
    const float4* spw4 = (const float4*)(smem + wave*512);
    float4 p0 = spw4[lane], p1 = spw4[lane + 64];
    float pv[8] = {p0.x,p0.y,p0.z,p0.w,p1.x,p1.y,p1.z,p1.w};
    #pragma unroll
    for (int i = 0; i < 8; i++){
      float pos = (pv[i] - leftS) * inv2;
      float n = floorf(pos + 0.5f);
      float d = pos - n;
      float wm = 0.5f*(0.5f-d)*(0.5f-d);
      float wp = 0.5f*(0.5f+d)*(0.5f+d);
      float w0 = 0.75f - d*d;
      int base = (int)n + 71;
      atomicAdd(&hf[base  ], wm);
      atomicAdd(&hf[base+1], w0);
      atomicAdd(&hf[base+2], wp);
    }
  }
  __syncthreads();
  // FIR conv, unroll 8 over zero-padded 72 taps (>=32 b64 loads in flight)
  float lenE = (float)dlen[wave*L_ + l];
  float rlen = 1.0f / lenE;
  float padc = 512.0f - lenE;
  {
    const float* sK = smem + 4672;
    const float* hb = smem + 2048 + wave*656;
    float a0=0.f, a1=0.f, a2=0.f, a3=0.f;
    #pragma unroll 8
    for (int uu = 0; uu < 72; uu++){
      float2 kv = *(const float2*)&sK[2*uu];
      int off = 2*(69 - uu) + 2*lane;        // may go to -4 for uu>69: tap=0
      float2 h0 = *(const float2*)&hb[off];
      float2 h1 = *(const float2*)&hb[off + 128];
      float2 h2 = *(const float2*)&hb[off + 256];
      float2 h3 = *(const float2*)&hb[off + 384];
      a0 = fmaf(h0.x, kv.x, fmaf(h0.y, kv.y, a0));
      a1 = fmaf(h1.x, kv.x, fmaf(h1.y, kv.y, a1));
      a2 = fmaf(h2.x, kv.x, fmaf(h2.y, kv.y, a2));
      a3 = fmaf(h3.x, kv.x, fmaf(h3.y, kv.y, a3));
    }
    const float* sCorr = smem + 4816;
    smem[wave*256 + lane      ] = (a0 - padc * sCorr[lane      ]) * rlen;
    smem[wave*256 + lane +  64] = (a1 - padc * sCorr[lane +  64]) * rlen;
    smem[wave*256 + lane + 128] = (a2 - padc * sCorr[lane + 128]) * rlen;
    smem[wave*256 + lane + 192] = (a3 - padc * sCorr[lane + 192]) * rlen;
  }
  __syncthreads();
  // fine grid: 4-pt Lagrange cubic on st, then pairwise L1
  float ps[6] = {0,0,0,0,0,0};
  #pragma unroll
  for (int r=0;r<4;r++){
    int t = tid + 256*r;
    if (t < S_){
      int cc = t >> 2;
      float u = (float)(t & 3) * 0.25f;
      float um1 = u - 1.0f, um2 = u - 2.0f, up1 = u + 1.0f;
      float w0 = -u * um1 * um2 * (1.0f/6.0f);
      float w1 = up1 * um1 * um2 * 0.5f;
      float w2 = -u * up1 * um2 * 0.5f;
      float w3 = u * up1 * um1 * (1.0f/6.0f);
      float rr[4];
      #pragma unroll
      for (int e=0;e<4;e++){
        const float* st = &smem[e*256 + cc];
        rr[e] = w0*st[0] + w1*st[1] + w2*st[2] + w3*st[3];
      }
      ps[0] += fabsf(rr[0]-rr[1]);
      ps[1] += fabsf(rr[0]-rr[2]);
      ps[2] += fabsf(rr[0]-rr[3]);
      ps[3] += fabsf(rr[1]-rr[2]);
      ps[4] += fabsf(rr[1]-rr[3]);
      ps[5] += fabsf(rr[2]-rr[3]);
    }
  }
  #pragma unroll
  for (int pr=0; pr<6; pr++){
    float v = ps[pr];
    #pragma unroll
    for (int d=32; d>=1; d>>=1) v += __shfl_xor(v, d, 64);
    if (lane == 0) smem[5072 + wave*8 + pr] = v;
  }
  __syncthreads();
  if (tid < 6)
    dpair[tid*1280 + b] = smem[5072+tid] + smem[5080+tid] + smem[5088+tid] + smem[5096+tid];
}

// merged finalize: scale, masked max over pairs, then max over L + mean over F
__global__ void k_fin(const float* __restrict__ dpair, const float* __restrict__ wsf,
                      const int* __restrict__ istrain, float* __restrict__ out){
  __shared__ float str[1280], ste[1280];
  __shared__ float s1[128], s2[128];
  int tid = threadIdx.x;   // 256 threads, 1 block
  float hscale = wsf[8+3];
  bool t0 = istrain[0]!=0, t1 = istrain[1]!=0, t2 = istrain[2]!=0, t3 = istrain[3]!=0;
  bool trn[6] = { t0&&t1, t0&&t2, t0&&t3, t1&&t2, t1&&t3, t2&&t3 };
  for (int idx = tid; idx < 1280; idx += 256){
    float tmax = -INFINITY, trmax = -INFINITY;
    #pragma unroll
    for (int pr=0;pr<6;pr++){
      float h = dpair[pr*1280 + idx] * hscale;
      tmax = fmaxf(tmax, h);
      if (trn[pr]) trmax = fmaxf(trmax, h);
    }
    out[idx]        = trmax;   // train_results
    out[1280 + idx] = tmax;    // test_results
    str[idx] = trmax; ste[idx] = tmax;
  }
  __syncthreads();
  if (tid < 128){
    float m1 = -INFINITY, m2 = -INFINITY;
    for (int l=0;l<L_;l++){
      m1 = fmaxf(m1, str[l*F_ + tid]);
      m2 = fmaxf(m2, ste[l*F_ + tid]);
    }
    s1[tid] = m1; s2[tid] = m2;
  }
  __syncthreads();
  for (int g=64; g>=1; g>>=1){
    if (tid < g){ s1[tid] += s1[tid+g]; s2[tid] += s2[tid+g]; }
    __syncthreads();
  }
  if (tid == 0){
    out[2560] = s1[0] * (1.0f/128.0f);
    out[2561] = s2[0] * (1.0f/128.0f);
  }
}

extern "C" void kernel_launch(void* const* d_in, const int* in_sizes, int n_in,
                              void* d_out, int out_size, void* d_ws, size_t ws_size,
                              hipStream_t stream){
  const float* mat = (const float*)d_in[0];
  const float* par = (const float*)d_in[1];
  const int*  dlen = (const int*)d_in[2];
  const int*  istr = (const int*)d_in[3];
  float* out   = (float*)d_out;
  float* wsf   = (float*)d_ws;
  float* dpair = wsf + 10752;
  float* projT = wsf + 18432;

  // host-computable constants (bw's data-dependent factor is identically 1)
  double bw_d   = 1.06 * pow(512.0, -0.2);
  float  bw     = (float)bw_d;
  float  offset = expf(-0.5f / (bw*bw));
  float  k2c    = (float)(log((double)offset) * 1.4426950408889634);  // log2(offset)
  float  divisor = sqrtf(6.283185307179586f) * bw;

  k_std  <<<40,   512, 0, stream>>>(mat, wsf);
  k_gemm <<<1280, 256, 0, stream>>>(mat, par, projT, wsf);
  k_red  <<<1,    256, 0, stream>>>(wsf, k2c, divisor);
  k_kde  <<<1280, 256, 0, stream>>>(projT, dlen, wsf, dpair);
  k_fin  <<<1,    256, 0, stream>>>(dpair, wsf, istr, out);
}

// Round 7
// 158.288 us; speedup vs baseline: 1.2461x; 1.1519x over previous
//
#include <hip/hip_runtime.h>
#include <cmath>

#define E_ 4
#define L_ 10
#define M_ 512
#define F_ 128
#define S_ 1000

typedef unsigned int u32;
typedef _Float16 f16;
typedef __attribute__((ext_vector_type(8))) _Float16 v8h;
typedef __attribute__((ext_vector_type(4))) float v4f;

__device__ __forceinline__ float fexp2(float a){
#if __has_builtin(__builtin_amdgcn_exp2f)
  return __builtin_amdgcn_exp2f(a);
#else
  return exp2f(a);
#endif
}

// ws float layout (total 282640 <= 288768 proven available):
// [8]            hscale (written by k_kde block 0, read by k_fin)
// [16..1296)     per-gemm-block min   (unique slot per block, no init needed)
// [1296..2576)   per-gemm-block max
// [2576..7696)   std S1 partials [40][128]
// [7696..12816)  std S2 partials [40][128]
// [12816..20496) dpair[6][1280]
// [20496..282640) projT[E][L][F][M] (unscaled, m contiguous)

// blocks 0..1279: MFMA f16 GEMM tile (direct global loads/stores) + block min/max
// blocks 1280..1319: per-(e,l) std partial sums
__global__ __launch_bounds__(256) void k_pre(const float* __restrict__ mat,
                       const float* __restrict__ par,
                       float* __restrict__ projT, float* __restrict__ wsf){
  __shared__ float sm[512];
  int b = blockIdx.x, tid = threadIdx.x;
  if (b >= 1280){
    int el = b - 1280;
    int f = tid & 127, part = tid >> 7;
    const float* base = mat + ((size_t)el * M_ + part*256) * F_;
    float s = 0.f, s2 = 0.f;
    for (int i = 0; i < 256; i++){
      float v = base[i*F_ + f];
      s += v; s2 += v*v;
    }
    sm[tid] = s; sm[256 + tid] = s2;
    __syncthreads();
    if (tid < 128){
      wsf[2576 + el*128 + tid] = sm[tid] + sm[tid+128];
      wsf[7696 + el*128 + tid] = sm[256+tid] + sm[256+tid+128];
    }
    return;
  }
  int el = b >> 5, mt = (b & 31) * 16;
  int lane = tid & 63, wave = tid >> 6;
  int q = (lane >> 4) & 3, m16 = lane & 15;
  const float* arow = mat + ((size_t)el * M_ + mt + m16) * F_;
  v4f acc0 = {0.f,0.f,0.f,0.f}, acc1 = {0.f,0.f,0.f,0.f};
  #pragma unroll
  for (int c = 0; c < 4; c++){
    float4 a0 = *(const float4*)&arow[c*32 + q*8];
    float4 a1 = *(const float4*)&arow[c*32 + q*8 + 4];
    v8h af, b0, b1;
    af[0]=(f16)a0.x; af[1]=(f16)a0.y; af[2]=(f16)a0.z; af[3]=(f16)a0.w;
    af[4]=(f16)a1.x; af[5]=(f16)a1.y; af[6]=(f16)a1.z; af[7]=(f16)a1.w;
    const float* pb = par + (c*32 + q*8)*F_ + wave*32 + m16;
    #pragma unroll
    for (int j = 0; j < 8; j++){
      b0[j] = (f16)pb[j*F_];
      b1[j] = (f16)pb[j*F_ + 16];
    }
    acc0 = __builtin_amdgcn_mfma_f32_16x16x32_f16(af, b0, acc0, 0, 0, 0);
    acc1 = __builtin_amdgcn_mfma_f32_16x16x32_f16(af, b1, acc1, 0, 0, 0);
  }
  // direct stores: C/D row=q*4+r (m), col=m16 (n) -> projT[el][n][m]
  *(float4*)(projT + ((size_t)el*F_ + wave*32      + m16)*M_ + mt + q*4)
      = make_float4(acc0[0], acc0[1], acc0[2], acc0[3]);
  *(float4*)(projT + ((size_t)el*F_ + wave*32 + 16 + m16)*M_ + mt + q*4)
      = make_float4(acc1[0], acc1[1], acc1[2], acc1[3]);
  float lmin =  3.4e38f, lmax = -3.4e38f;
  #pragma unroll
  for (int r = 0; r < 4; r++){
    lmin = fminf(lmin, fminf(acc0[r], acc1[r]));
    lmax = fmaxf(lmax, fmaxf(acc0[r], acc1[r]));
  }
  #pragma unroll
  for (int d = 32; d >= 1; d >>= 1){
    lmin = fminf(lmin, __shfl_xor(lmin, d, 64));
    lmax = fmaxf(lmax, __shfl_xor(lmax, d, 64));
  }
  if (lane == 0){ sm[wave] = lmin; sm[8+wave] = lmax; }
  __syncthreads();
  if (tid == 0){
    wsf[16   + b] = fminf(fminf(sm[0], sm[1]), fminf(sm[2], sm[3]));
    wsf[1296 + b] = fmaxf(fmaxf(sm[8], sm[9]), fmaxf(sm[10], sm[11]));
  }
}

// KDE with inline reduction prologue:
// smem: p/st [0..2048) | scratch->hist [2048..4672) | taps [4672..4816) |
//       corr [4816..5072) | consts+red [5072..5104)
__global__ __launch_bounds__(256) void k_kde(const float* __restrict__ projT,
                      const int* __restrict__ dlen, float* __restrict__ wsf,
                      float* __restrict__ dpair, float k2c, float divisor){
  __shared__ __align__(16) float smem[5104];
  int b = blockIdx.x;          // 0..1279
  int l = b >> 7, f = b & 127;
  int tid = threadIdx.x, wave = tid >> 6, lane = tid & 63;
  // stage p UNSCALED (rstd folded into splat constants later)
  for (int idx = tid; idx < 512; idx += 256){
    int e = idx >> 7, mq = idx & 127;
    ((float4*)smem)[idx] =
      ((const float4*)(projT + (((size_t)e * L_ + l) * F_ + f) * M_))[mq];
  }
  // inline reduction: global min/max over 1280 block slots + sum of 5120 stds
  float mn = 3.4e38f, mx = -3.4e38f, s = 0.f;
  for (int i = tid; i < 1280; i += 256){
    mn = fminf(mn, wsf[16   + i]);
    mx = fmaxf(mx, wsf[1296 + i]);
  }
  for (int i = tid; i < 5120; i += 256){
    float a  = wsf[2576 + i];
    float a2 = wsf[7696 + i];
    float mean = a * (1.0f/512.0f);
    float var  = a2 * (1.0f/512.0f) - mean*mean;
    s += sqrtf(fmaxf(var, 0.0f));
  }
  smem[2048+tid] = mn; smem[2304+tid] = mx; smem[2560+tid] = s;
  __syncthreads();
  for (int g = 128; g >= 1; g >>= 1){
    if (tid < g){
      smem[2048+tid] = fminf(smem[2048+tid], smem[2048+tid+g]);
      smem[2304+tid] = fmaxf(smem[2304+tid], smem[2304+tid+g]);
      smem[2560+tid] += smem[2560+tid+g];
    }
    __syncthreads();
  }
  if (tid == 0){
    float rstd   = 5120.0f / smem[2560];
    float leftS  = smem[2048] * rstd;
    float rightS = smem[2304] * rstd;
    float stepFS = (rightS - leftS) * (1.0f/999.0f);
    float inv2   = 1.0f / (2.0f * stepFS);
    smem[5072] = rstd * inv2;    // posScale
    smem[5073] = leftS * inv2;   // posOff
    smem[5074] = stepFS;
    smem[5075] = leftS;
    if (b == 0)
      wsf[8] = ((rightS - leftS) * (1.0f/1000.0f)) * 0.5f / divisor;
  }
  __syncthreads();
  float posScale = smem[5072], posOff = smem[5073];
  float stepFS = smem[5074], leftS = smem[5075];
  __syncthreads();   // all reads of consts done before red-area reuse at end
  // zero hist (overwrites scratch) + build tap/corr tables
  for (int idx = tid; idx < 656; idx += 256)
    ((float4*)(smem + 2048))[idx] = make_float4(0.f,0.f,0.f,0.f);
  float sh = 2.0f * stepFS;
  if (tid < 72){
    int u = tid - 34;
    float d0 = (float)(2*u)   * sh;
    float d1 = (float)(2*u-1) * sh;
    float2 t = (tid < 69) ? make_float2(fexp2(k2c*d0*d0), fexp2(k2c*d1*d1))
                          : make_float2(0.f, 0.f);
    *(float2*)&smem[4672 + 2*tid] = t;
  }
  {
    float xc = fmaf((float)(tid - 1), 4.0f*stepFS, leftS);
    smem[4816 + tid] = fexp2(k2c * xc * xc);
  }
  __syncthreads();
  // quadratic (TSC) splat; wave w owns env w's histogram
  {
    float* hf = smem + 2048 + wave*656;
    const float4* spw4 = (const float4*)(smem + wave*512);
    float4 p0 = spw4[lane], p1 = spw4[lane + 64];
    float pv[8] = {p0.x,p0.y,p0.z,p0.w,p1.x,p1.y,p1.z,p1.w};
    #pragma unroll
    for (int i = 0; i < 8; i++){
      float pos = fmaf(pv[i], posScale, -posOff);
      float n = floorf(pos + 0.5f);
      float d = pos - n;
      float wm = 0.5f*(0.5f-d)*(0.5f-d);
      float wp = 0.5f*(0.5f+d)*(0.5f+d);
      float w0 = 0.75f - d*d;
      int base = (int)n + 71;
      atomicAdd(&hf[base  ], wm);
      atomicAdd(&hf[base+1], w0);
      atomicAdd(&hf[base+2], wp);
    }
  }
  __syncthreads();
  // FIR conv, unroll 8 over zero-padded 72 taps
  float lenE = (float)dlen[wave*L_ + l];
  float rlen = 1.0f / lenE;
  float padc = 512.0f - lenE;
  {
    const float* sK = smem + 4672;
    const float* hb = smem + 2048 + wave*656;
    float a0=0.f, a1=0.f, a2=0.f, a3=0.f;
    #pragma unroll 8
    for (int uu = 0; uu < 72; uu++){
      float2 kv = *(const float2*)&sK[2*uu];
      int off = 2*(69 - uu) + 2*lane;        // may reach -4 for uu>69: tap=0
      float2 h0 = *(const float2*)&hb[off];
      float2 h1 = *(const float2*)&hb[off + 128];
      float2 h2 = *(const float2*)&hb[off + 256];
      float2 h3 = *(const float2*)&hb[off + 384];
      a0 = fmaf(h0.x, kv.x, fmaf(h0.y, kv.y, a0));
      a1 = fmaf(h1.x, kv.x, fmaf(h1.y, kv.y, a1));
      a2 = fmaf(h2.x, kv.x, fmaf(h2.y, kv.y, a2));
      a3 = fmaf(h3.x, kv.x, fmaf(h3.y, kv.y, a3));
    }
    const float* sCorr = smem + 4816;
    smem[wave*256 + lane      ] = (a0 - padc * sCorr[lane      ]) * rlen;
    smem[wave*256 + lane +  64] = (a1 - padc * sCorr[lane +  64]) * rlen;
    smem[wave*256 + lane + 128] = (a2 - padc * sCorr[lane + 128]) * rlen;
    smem[wave*256 + lane + 192] = (a3 - padc * sCorr[lane + 192]) * rlen;
  }
  __syncthreads();
  // fine grid: 4-pt Lagrange cubic on st, then pairwise L1
  float ps[6] = {0,0,0,0,0,0};
  #pragma unroll
  for (int r=0;r<4;r++){
    int t = tid + 256*r;
    if (t < S_){
      int cc = t >> 2;
      float u = (float)(t & 3) * 0.25f;
      float um1 = u - 1.0f, um2 = u - 2.0f, up1 = u + 1.0f;
      float w0 = -u * um1 * um2 * (1.0f/6.0f);
      float w1 = up1 * um1 * um2 * 0.5f;
      float w2 = -u * up1 * um2 * 0.5f;
      float w3 = u * up1 * um1 * (1.0f/6.0f);
      float rr[4];
      #pragma unroll
      for (int e=0;e<4;e++){
        const float* st = &smem[e*256 + cc];
        rr[e] = w0*st[0] + w1*st[1] + w2*st[2] + w3*st[3];
      }
      ps[0] += fabsf(rr[0]-rr[1]);
      ps[1] += fabsf(rr[0]-rr[2]);
      ps[2] += fabsf(rr[0]-rr[3]);
      ps[3] += fabsf(rr[1]-rr[2]);
      ps[4] += fabsf(rr[1]-rr[3]);
      ps[5] += fabsf(rr[2]-rr[3]);
    }
  }
  #pragma unroll
  for (int pr=0; pr<6; pr++){
    float v = ps[pr];
    #pragma unroll
    for (int d=32; d>=1; d>>=1) v += __shfl_xor(v, d, 64);
    if (lane == 0) smem[5072 + wave*8 + pr] = v;
  }
  __syncthreads();
  if (tid < 6)
    dpair[tid*1280 + b] = smem[5072+tid] + smem[5080+tid] + smem[5088+tid] + smem[5096+tid];
}

// finalize: scale, masked max over pairs, then max over L + mean over F
__global__ void k_fin(const float* __restrict__ dpair, const float* __restrict__ wsf,
                      const int* __restrict__ istrain, float* __restrict__ out){
  __shared__ float str[1280], ste[1280];
  __shared__ float s1[128], s2[128];
  int tid = threadIdx.x;   // 256 threads, 1 block
  float hscale = wsf[8];
  bool t0 = istrain[0]!=0, t1 = istrain[1]!=0, t2 = istrain[2]!=0, t3 = istrain[3]!=0;
  bool trn[6] = { t0&&t1, t0&&t2, t0&&t3, t1&&t2, t1&&t3, t2&&t3 };
  for (int idx = tid; idx < 1280; idx += 256){
    float tmax = -INFINITY, trmax = -INFINITY;
    #pragma unroll
    for (int pr=0;pr<6;pr++){
      float h = dpair[pr*1280 + idx] * hscale;
      tmax = fmaxf(tmax, h);
      if (trn[pr]) trmax = fmaxf(trmax, h);
    }
    out[idx]        = trmax;   // train_results
    out[1280 + idx] = tmax;    // test_results
    str[idx] = trmax; ste[idx] = tmax;
  }
  __syncthreads();
  if (tid < 128){
    float m1 = -INFINITY, m2 = -INFINITY;
    for (int l=0;l<L_;l++){
      m1 = fmaxf(m1, str[l*F_ + tid]);
      m2 = fmaxf(m2, ste[l*F_ + tid]);
    }
    s1[tid] = m1; s2[tid] = m2;
  }
  __syncthreads();
  for (int g=64; g>=1; g>>=1){
    if (tid < g){ s1[tid] += s1[tid+g]; s2[tid] += s2[tid+g]; }
    __syncthreads();
  }
  if (tid == 0){
    out[2560] = s1[0] * (1.0f/128.0f);
    out[2561] = s2[0] * (1.0f/128.0f);
  }
}

extern "C" void kernel_launch(void* const* d_in, const int* in_sizes, int n_in,
                              void* d_out, int out_size, void* d_ws, size_t ws_size,
                              hipStream_t stream){
  const float* mat = (const float*)d_in[0];
  const float* par = (const float*)d_in[1];
  const int*  dlen = (const int*)d_in[2];
  const int*  istr = (const int*)d_in[3];
  float* out   = (float*)d_out;
  float* wsf   = (float*)d_ws;
  float* dpair = wsf + 12816;
  float* projT = wsf + 20496;

  // host-computable constants (bw's data-dependent factor is identically 1)
  double bw_d   = 1.06 * pow(512.0, -0.2);
  float  bw     = (float)bw_d;
  float  offset = expf(-0.5f / (bw*bw));
  float  k2c    = (float)(log((double)offset) * 1.4426950408889634);  // log2(offset)
  float  divisor = sqrtf(6.283185307179586f) * bw;

  k_pre <<<1320, 256, 0, stream>>>(mat, par, projT, wsf);
  k_kde <<<1280, 256, 0, stream>>>(projT, dlen, wsf, dpair, k2c, divisor);
  k_fin <<<1,    256, 0, stream>>>(dpair, wsf, istr, out);
}